// Round 14
// baseline (13869.402 us; speedup 1.0000x reference)
//
#include <hip/hip_runtime.h>

#define B_TOT 1024
#define L_T   100
#define DIN   32
#define HID   128
#define DOUT  32
#define BT    8       // batch rows per block
#define NBLK  128     // 1024 / 8 -> 128 CUs, 1 block/CU (LDS-forced)
#define NTHREADS 512  // 8 waves (512-thread blocks get >64 VGPR budget)

typedef _Float16 half8 __attribute__((ext_vector_type(8)));
typedef float    f32x4 __attribute__((ext_vector_type(4)));

// XOR-swizzled index into a [16][128] f16 LDS tile (bank-conflict-free b128 reads)
#define SWZ(r,c) (((r) << 7) + ((c) ^ (((r) & 7) << 3)))

__device__ __forceinline__ float fast_exp2(float x){
#if __has_builtin(__builtin_amdgcn_exp2f)
  return __builtin_amdgcn_exp2f(x);
#else
  float r; asm("v_exp_f32 %0, %1\n\ts_nop 1" : "=v"(r) : "v"(x)); return r;
#endif
}
__device__ __forceinline__ float fast_rcp(float x){
#if __has_builtin(__builtin_amdgcn_rcpf)
  return __builtin_amdgcn_rcpf(x);
#else
  float r; asm("v_rcp_f32 %0, %1\n\ts_nop 1" : "=v"(r) : "v"(x)); return r;
#endif
}
__device__ __forceinline__ float fast_tanh(float x){
  float e = fast_exp2(x * 2.885390081777926f);  // 2*log2(e)
  return 1.0f - 2.0f * fast_rcp(e + 1.0f);
}

// Reorder [N][K] f32 row-major weights into fragment-ready f16 tiles:
// dst[((tile*(K/32)+k0)*64 + lane)*8 + ki], lane = (n&15) + 16*((k>>3)&3)
__global__ void reorder_w(const float* __restrict__ src, _Float16* __restrict__ dst,
                          int N, int K){
  int id = blockIdx.x * 256 + threadIdx.x;
  if (id >= N * K) return;
  int n = id / K, k = id - n * K;
  int tile = n >> 4, nl = n & 15;
  int kq = (k >> 3) & 3, k0 = k >> 5, ki = k & 7;
  int lane = nl + (kq << 4);
  int K32 = K >> 5;
  dst[(((tile * K32 + k0) << 6) + lane) * 8 + ki] = (_Float16)src[id];
}

// async global->LDS, 16B/lane: LDS dest is wave-uniform base (HW adds lane*16),
// global src is per-lane. Bypasses the VGPR return path entirely.
__device__ __forceinline__ void gload_lds16(const _Float16* g, _Float16* l){
  __builtin_amdgcn_global_load_lds(
      (const __attribute__((address_space(1))) void*)g,
      (__attribute__((address_space(3))) void*)l, 16, 0, 0);
}

// Round-14 probe: the Wf stream (1.125 MiB/stage/CU) runs at ~34 B/cyc with
// VGPR-return loads in 3 different schedules (r7/r10/r13). This swaps the
// load MECHANISM to global_load_lds DMA (3-deep per-wave LDS window, counted
// vmcnt, never drained mid-loop). If the ~34 B/cyc cap is CU-side (VGPR
// return port), this lifts it; if L2-side, the wall stays and that IS the
// roofline for the weight-stationary-per-CU structure.
__global__ __launch_bounds__(NTHREADS) void cde_main(
    const float* __restrict__ coeffs, const float* __restrict__ times,
    const float* __restrict__ init_b, const float* __restrict__ fb0,
    const float* __restrict__ fb1,    const float* __restrict__ fb2,
    const float* __restrict__ fbf,    const float* __restrict__ dec_b,
    const _Float16* __restrict__ W,   float* __restrict__ out)
{
  __shared__ _Float16 bufA[16*HID];  // activation ping-pong (16 rows; 8 valid)
  __shared__ _Float16 bufB[16*HID];
  __shared__ float zf[BT][HID];      // fp32 master z
  __shared__ float dzs[16][HID];     // vf output (16 rows; 8 valid) + init scratch
  __shared__ float kacc[BT][HID];    // RK4 k-accumulator
  __shared__ float dxs[16][DIN];     // dX/dt (rows 8-15 zeroed once)
  __shared__ float fbfs[HID*DIN];    // fwf bias (16 KiB)
  __shared__ _Float16 win[8][3][2048]; // per-wave 3-tile DMA window (96 KiB)
  // static LDS total = 141,312 B -> 1 block/CU (>81,920)

  const int tid  = threadIdx.x;
  const int lane = tid & 63;
  const int w    = tid >> 6;   // wave 0..7
  const int cl   = lane & 15;
  const int g    = lane >> 4;
  const int b0   = blockIdx.x * BT;

  const _Float16* W0 = W;
  const _Float16* W1 = W + 16384;
  const _Float16* W2 = W + 32768;
  const _Float16* Wf = W + 49152;   // fwf: 4096x128 -> 256 tiles
  const _Float16* Wi = W + 573440;  // init_w
  const _Float16* Wd = W + 577536;  // dec_w
  const _Float16* Wfw = Wf + w * 32 * 2048;  // this wave's 32 tiles (128 KiB)

  // lgkm-only barrier, two-sided compiler clobbers + sched_barrier pins.
  // vmcnt deliberately NOT drained: in-flight DMAs write wave-PRIVATE window
  // slots and may legally span barriers.
  auto bar = [&]{
    __builtin_amdgcn_sched_barrier(0);
    asm volatile("s_waitcnt lgkmcnt(0)" ::: "memory");
    __builtin_amdgcn_s_barrier();
    __builtin_amdgcn_sched_barrier(0);
    asm volatile("" ::: "memory");
  };

#define DMA_TILE(SLOT, IDX) {                                   \
    const _Float16* _g = Wfw + (IDX)*2048 + lane*8;             \
    _Float16* _l = &win[w][SLOT][0];                            \
    gload_lds16(_g,        _l);                                 \
    gload_lds16(_g +  512, _l +  512);                          \
    gload_lds16(_g + 1024, _l + 1024);                          \
    gload_lds16(_g + 1536, _l + 1536); }

  // fbf biases -> LDS (once); zero-init buffers so garbage rows stay finite
  for (int i = tid; i < HID*DIN; i += NTHREADS) fbfs[i] = fbf[i];
#pragma unroll
  for (int j = 0; j < 4; ++j){
    bufA[tid + 512*j] = (_Float16)0.f;
    bufB[tid + 512*j] = (_Float16)0.f;
  }
  dxs[tid >> 5][tid & 31] = 0.f;

  // ---- init: z0 = coeffs[:,0,:] @ init_w.T + init_b ----
  bar();
  if (tid < BT*DIN){
    int r = tid >> 5, d = tid & 31;
    bufB[SWZ(r, d)] = (_Float16)coeffs[(b0 + r)*(L_T*DIN) + d];
  }
  bar();
  {
    f32x4 acc = {0.f,0.f,0.f,0.f};
    half8 a = *(const half8*)(bufB + SWZ(cl, 8*g));
    half8 b = *(const half8*)(Wi + (w*64 + lane)*8);
    acc = __builtin_amdgcn_mfma_f32_16x16x32_f16(a, b, acc, 0, 0, 0);
    float bn = init_b[w*16 + cl];
#pragma unroll
    for (int r = 0; r < 4; ++r){
      float v = acc[r] + bn;
      dzs[4*g + r][w*16 + cl] = v;                  // f32 scratch (16 rows ok)
      bufA[SWZ(4*g + r, w*16 + cl)] = (_Float16)v;
    }
  }
  bar();
#pragma unroll
  for (int j = 0; j < 2; ++j){
    int e = tid + 512*j;
    zf[e >> 7][e & 127] = dzs[e >> 7][e & 127];
  }
  bar();

// Dense HID->HID, all 8 waves; B-fragments inline from L2-resident weights.
#define DENSE(IN, OB, WT, BIAS) {                                          \
    f32x4 acc = {0.f,0.f,0.f,0.f};                                         \
    _Pragma("unroll")                                                      \
    for (int kq = 0; kq < 4; ++kq){                                        \
      half8 a = *(const half8*)((IN) + SWZ(cl, kq*32 + 8*g));              \
      half8 b = *(const half8*)((WT) + ((w*4 + kq)*64 + lane)*8);          \
      acc = __builtin_amdgcn_mfma_f32_16x16x32_f16(a, b, acc, 0,0,0);}     \
    float bn = (BIAS)[w*16 + cl];                                          \
    _Pragma("unroll")                                                      \
    for (int r = 0; r < 4; ++r)                                            \
      (OB)[SWZ(4*g + r, w*16 + cl)] = (_Float16)fast_tanh(acc[r] + bn); }

#define DECODER(TS) {                                                      \
    int dw = w - 6;                                                        \
    f32x4 acc = {0.f,0.f,0.f,0.f};                                         \
    _Pragma("unroll")                                                      \
    for (int kq = 0; kq < 4; ++kq){                                        \
      half8 a = *(const half8*)(bufA + SWZ(cl, kq*32 + 8*g));              \
      half8 b = *(const half8*)(Wd + ((dw*4 + kq)*64 + lane)*8);           \
      acc = __builtin_amdgcn_mfma_f32_16x16x32_f16(a, b, acc, 0,0,0);}     \
    float bn = dec_b[dw*16 + cl];                                          \
    if (g < 2){                                                            \
      _Pragma("unroll")                                                    \
      for (int r = 0; r < 4; ++r)                                          \
        out[(b0 + 4*g + r)*(L_T*DOUT) + (TS)*DOUT + dw*16 + cl] = acc[r] + bn; } }

// One biglayer tile step. WAITN = 4*(tiles still wanted in flight):
// u<=29 -> 8 (tiles u+1,u+2 in flight), u==30 -> 4, u==31 -> 0.
// ds_reads of tile u complete (lgkmcnt 0) BEFORE DMA of u+3 reuses slot u%3.
#define BIG_STEP(U, WAITN) {                                                \
    asm volatile("s_waitcnt vmcnt(" #WAITN ")" ::: "memory");               \
    __builtin_amdgcn_sched_barrier(0);                                      \
    const _Float16* wp = &win[w][(U) % 3][0];                               \
    half8 f0 = *(const half8*)(wp +        lane*8);                         \
    half8 f1 = *(const half8*)(wp +  512 + lane*8);                         \
    half8 f2 = *(const half8*)(wp + 1024 + lane*8);                         \
    half8 f3 = *(const half8*)(wp + 1536 + lane*8);                         \
    float bn = fbfs[(w*32 + (U))*16 + cl];                                  \
    asm volatile("s_waitcnt lgkmcnt(0)" ::: "memory");                      \
    __builtin_amdgcn_sched_barrier(0);                                      \
    if ((U) + 3 < 32) DMA_TILE((U) % 3, (U) + 3)                            \
    __builtin_amdgcn_sched_barrier(0);                                      \
    f32x4 acc = {0.f,0.f,0.f,0.f};                                          \
    acc = __builtin_amdgcn_mfma_f32_16x16x32_f16(af[0], f0, acc, 0,0,0);    \
    acc = __builtin_amdgcn_mfma_f32_16x16x32_f16(af[1], f1, acc, 0,0,0);    \
    acc = __builtin_amdgcn_mfma_f32_16x16x32_f16(af[2], f2, acc, 0,0,0);    \
    acc = __builtin_amdgcn_mfma_f32_16x16x32_f16(af[3], f3, acc, 0,0,0);    \
    if (((U) & 1) == 0){                                                    \
      _Pragma("unroll")                                                     \
      for (int r = 0; r < 4; ++r) p[r] = fast_tanh(acc[r] + bn)*dxlo[r];    \
    } else {                                                                \
      _Pragma("unroll")                                                     \
      for (int r = 0; r < 4; ++r) p[r] += fast_tanh(acc[r] + bn)*dxhi[r];   \
      _Pragma("unroll")                                                     \
      for (int m = 1; m < 16; m <<= 1){                                     \
        _Pragma("unroll")                                                   \
        for (int r = 0; r < 4; ++r) p[r] += __shfl_xor(p[r], m, 64);        \
      }                                                                     \
      if (cl == 0){                                                         \
        _Pragma("unroll")                                                   \
        for (int r = 0; r < 4; ++r) dzs[4*g + r][w*16 + ((U) >> 1)] = p[r]; \
      }                                                                     \
    } }

  float dxlo[4], dxhi[4];

  for (int t = 0; t < L_T - 1; ++t){
    // decoder(t) on waves 6-7: bufA (=z_t) is not rewritten until s=0's
    // combine, 4 barriers after these ds_reads drain (at this wave's bar()).
    if (w >= 6) DECODER(t)

    float dt = times[t+1] - times[t];
    if (tid < BT*DIN){
      int r = tid >> 5, d = tid & 31;
      const float* cp = coeffs + (b0 + r)*(L_T*DIN) + t*DIN + d;
      dxs[r][d] = (cp[DIN] - cp[0]) / dt;
    }
    bar();
#pragma unroll
    for (int r = 0; r < 4; ++r){
      dxlo[r] = dxs[4*g + r][cl];        // rows 8-15: zeros -> garbage rows x0
      dxhi[r] = dxs[4*g + r][16 + cl];
    }

    for (int s = 0; s < 4; ++s){
      // prime 3 window slots; DMAs stream in during the dense phases
      DMA_TILE(0, 0) DMA_TILE(1, 1) DMA_TILE(2, 2)

      DENSE(bufA, bufB, W0, fb0)
      bar();
      DENSE(bufB, bufA, W1, fb1)
      bar();
      DENSE(bufA, bufB, W2, fb2)
      bar();

      // ---- biglayer: 8 waves, 32 tiles each, DMA-fed, counted vmcnt
      {
        half8 af[4];
#pragma unroll
        for (int kq = 0; kq < 4; ++kq)
          af[kq] = *(const half8*)(bufB + SWZ(cl, kq*32 + 8*g));
        float p[4];
        BIG_STEP(0,8)  BIG_STEP(1,8)  BIG_STEP(2,8)  BIG_STEP(3,8)
        BIG_STEP(4,8)  BIG_STEP(5,8)  BIG_STEP(6,8)  BIG_STEP(7,8)
        BIG_STEP(8,8)  BIG_STEP(9,8)  BIG_STEP(10,8) BIG_STEP(11,8)
        BIG_STEP(12,8) BIG_STEP(13,8) BIG_STEP(14,8) BIG_STEP(15,8)
        BIG_STEP(16,8) BIG_STEP(17,8) BIG_STEP(18,8) BIG_STEP(19,8)
        BIG_STEP(20,8) BIG_STEP(21,8) BIG_STEP(22,8) BIG_STEP(23,8)
        BIG_STEP(24,8) BIG_STEP(25,8) BIG_STEP(26,8) BIG_STEP(27,8)
        BIG_STEP(28,8) BIG_STEP(29,8) BIG_STEP(30,4) BIG_STEP(31,0)
      }
      bar();

      // ---- RK4 combine (1024 valid elems, 2 per thread)
#pragma unroll
      for (int j = 0; j < 2; ++j){
        int e = tid + 512*j;
        int cr = e >> 7, ccol = e & 127;
        float kv = dzs[cr][ccol];
        float nin;
        if (s == 0){ kacc[cr][ccol] = kv;            nin = zf[cr][ccol] + 0.5f*dt*kv; }
        else if (s == 1){ kacc[cr][ccol] += 2.0f*kv; nin = zf[cr][ccol] + 0.5f*dt*kv; }
        else if (s == 2){ kacc[cr][ccol] += 2.0f*kv; nin = zf[cr][ccol] + dt*kv; }
        else {
          float zn = zf[cr][ccol] + (dt * (1.0f/6.0f)) * (kacc[cr][ccol] + kv);
          zf[cr][ccol] = zn; nin = zn;
        }
        bufA[SWZ(cr, ccol)] = (_Float16)nin;
      }
      bar();
    }
  }
  if (w >= 6) DECODER(L_T - 1)
}

extern "C" void kernel_launch(void* const* d_in, const int* in_sizes, int n_in,
                              void* d_out, int out_size, void* d_ws, size_t ws_size,
                              hipStream_t stream){
  const float* coeffs = (const float*)d_in[0];
  const float* times  = (const float*)d_in[1];
  const float* init_w = (const float*)d_in[2];
  const float* init_b = (const float*)d_in[3];
  const float* fw0    = (const float*)d_in[4];
  const float* fb0    = (const float*)d_in[5];
  const float* fw1    = (const float*)d_in[6];
  const float* fb1    = (const float*)d_in[7];
  const float* fw2    = (const float*)d_in[8];
  const float* fb2    = (const float*)d_in[9];
  const float* fwf    = (const float*)d_in[10];
  const float* fbf    = (const float*)d_in[11];
  const float* dec_w  = (const float*)d_in[12];
  const float* dec_b  = (const float*)d_in[13];
  _Float16* W = (_Float16*)d_ws;

  hipLaunchKernelGGL(reorder_w, dim3(64),   dim3(256), 0, stream, fw0, W,          128, 128);
  hipLaunchKernelGGL(reorder_w, dim3(64),   dim3(256), 0, stream, fw1, W + 16384,  128, 128);
  hipLaunchKernelGGL(reorder_w, dim3(64),   dim3(256), 0, stream, fw2, W + 32768,  128, 128);
  hipLaunchKernelGGL(reorder_w, dim3(2048), dim3(256), 0, stream, fwf, W + 49152,  4096, 128);
  hipLaunchKernelGGL(reorder_w, dim3(16),   dim3(256), 0, stream, init_w, W + 573440, 128, 32);
  hipLaunchKernelGGL(reorder_w, dim3(16),   dim3(256), 0, stream, dec_w,  W + 577536,  32, 128);

  hipLaunchKernelGGL(cde_main, dim3(NBLK), dim3(NTHREADS), 0, stream,
                     coeffs, times, init_b, fb0, fb1, fb2, fbf, dec_b,
                     W, (float*)d_out);
}

// Round 16
// 7967.886 us; speedup vs baseline: 1.7407x; 1.7407x over previous
//
#include <hip/hip_runtime.h>

#define B_TOT 1024
#define L_T   100
#define DIN   32
#define HID   128
#define DOUT  32
#define BT    32      // batch rows per block
#define NHG   8       // h-groups (fwf split 8 ways -> 128 KiB LDS slice)
#define NBLK  256     // 32 batch-tiles x 8 h-groups = 256 CUs, 1 block/CU
#define NTHREADS 1024 // 16 waves

typedef _Float16 half8 __attribute__((ext_vector_type(8)));
typedef float    f32x4 __attribute__((ext_vector_type(4)));

// XOR-swizzled index into a [rows][128] f16 LDS tile (conflict-free b128 reads)
#define SWZ(r,c) (((r) << 7) + ((c) ^ (((r) & 7) << 3)))

__device__ __forceinline__ float fast_exp2(float x){
#if __has_builtin(__builtin_amdgcn_exp2f)
  return __builtin_amdgcn_exp2f(x);
#else
  float r; asm("v_exp_f32 %0, %1\n\ts_nop 1" : "=v"(r) : "v"(x)); return r;
#endif
}
__device__ __forceinline__ float fast_rcp(float x){
#if __has_builtin(__builtin_amdgcn_rcpf)
  return __builtin_amdgcn_rcpf(x);
#else
  float r; asm("v_rcp_f32 %0, %1\n\ts_nop 1" : "=v"(r) : "v"(x)); return r;
#endif
}
__device__ __forceinline__ float fast_tanh(float x){
  float e = fast_exp2(x * 2.885390081777926f);  // 2*log2(e)
  return 1.0f - 2.0f * fast_rcp(e + 1.0f);
}

// Reorder [N][K] f32 row-major weights into fragment-ready f16 tiles:
// dst[((tile*(K/32)+k0)*64 + lane)*8 + ki], lane = (n&15) + 16*((k>>3)&3)
__global__ void reorder_w(const float* __restrict__ src, _Float16* __restrict__ dst,
                          int N, int K){
  int id = blockIdx.x * 256 + threadIdx.x;
  if (id >= N * K) return;
  int n = id / K, k = id - n * K;
  int tile = n >> 4, nl = n & 15;
  int kq = (k >> 3) & 3, k0 = k >> 5, ki = k & 7;
  int lane = nl + (kq << 4);
  int K32 = K >> 5;
  dst[(((tile * K32 + k0) << 6) + lane) * 8 + ki] = (_Float16)src[id];
}

// Round-9 h-split structure (fwf LDS-resident, compute verified, absmax
// 0.03125) with grid.sync() replaced by per-batch-group flag sync: only the
// 8 blocks sharing a batch-tile rendezvous per stage. Release = threadfence
// (wbl2) + relaxed atomicAdd; acquire = spin + threadfence (inv). Epochs are
// monotonic; dz double-buffered by stage parity (max skew 1 -> 2 bufs ok).
__global__ __launch_bounds__(NTHREADS) void cde_main(
    const float* __restrict__ coeffs, const float* __restrict__ times,
    const float* __restrict__ init_b, const float* __restrict__ fb0,
    const float* __restrict__ fb1,    const float* __restrict__ fb2,
    const float* __restrict__ fbf,    const float* __restrict__ dec_b,
    const _Float16* __restrict__ W,   float* __restrict__ dzg,
    unsigned int* __restrict__ flags, float* __restrict__ out)
{
  __shared__ _Float16 wslice[32*2048]; // 128 KiB: this block's fwf tiles (resident)
  __shared__ _Float16 bufA[BT*HID];    // 8 KiB ping-pong activations (f16, swizzled)
  __shared__ _Float16 bufB[BT*HID];    // 8 KiB
  __shared__ float    dzs[BT][16];     // 2 KiB  dz slice staging
  __shared__ float    dxs[BT][DIN];    // 4 KiB  dX/dt
  __shared__ float    fbfs[512];       // 2 KiB  fbf slice
  // total 155,648 B < 160 KiB

  const int tid  = threadIdx.x;
  const int lane = tid & 63;
  const int w    = tid >> 6;   // wave 0..15
  const int cl   = lane & 15;
  const int g    = lane >> 4;
  const int hg   = blockIdx.x & 7;   // h-group
  const int bt   = blockIdx.x >> 3;  // batch tile
  const int b0   = bt * BT;
  const int cr   = tid >> 5;         // combine row 0..31
  const int cc   = (tid & 31) * 4;   // combine col base

  const _Float16* W0 = W;
  const _Float16* W1 = W + 16384;
  const _Float16* W2 = W + 32768;
  const _Float16* Wf = W + 49152;   // fwf: 256 tiles
  const _Float16* Wi = W + 573440;  // init_w
  const _Float16* Wd = W + 577536;  // dec_w
  const _Float16* Wfs = Wf + hg * 32 * 2048;  // this block's 32 tiles
  unsigned int* flag = flags + bt * 32;       // 128B-strided counter per group

  // lgkm-only local barrier (two-sided clobbers + sched pins).
  auto bar = [&]{
    __builtin_amdgcn_sched_barrier(0);
    asm volatile("s_waitcnt lgkmcnt(0)" ::: "memory");
    __builtin_amdgcn_s_barrier();
    __builtin_amdgcn_sched_barrier(0);
    asm volatile("" ::: "memory");
  };

  // fbf slice (global idx = 512*hg + t_local*16 + nl)
  if (tid < 512) fbfs[tid] = fbf[hg*512 + tid];

  // ---- init: z0 = coeffs[:,0,:] @ init_w.T + init_b (wslice as f32 scratch)
  float* scratch = (float*)wslice;   // [32][128] f32, overwritten later
  {
    int r = tid >> 5, d = tid & 31;
    bufB[SWZ(r, d)] = (_Float16)coeffs[(b0 + r)*(L_T*DIN) + d];
  }
  bar();
  {
    const int rt = w >> 3, ct = w & 7;
    f32x4 acc = {0.f,0.f,0.f,0.f};
    half8 a = *(const half8*)(bufB + SWZ(rt*16 + cl, 8*g));
    half8 b = *(const half8*)(Wi + (ct*64 + lane)*8);
    acc = __builtin_amdgcn_mfma_f32_16x16x32_f16(a, b, acc, 0, 0, 0);
    float bn = init_b[ct*16 + cl];
#pragma unroll
    for (int r = 0; r < 4; ++r){
      float v = acc[r] + bn;
      scratch[(rt*16 + 4*g + r)*128 + ct*16 + cl] = v;
      bufA[SWZ(rt*16 + 4*g + r, ct*16 + cl)] = (_Float16)v;
    }
  }
  bar();
  float zf[4], ka[4] = {0.f,0.f,0.f,0.f};
#pragma unroll
  for (int j = 0; j < 4; ++j) zf[j] = scratch[cr*128 + cc + j];
  bar();
  // ---- fwf slice -> LDS (once; replaces scratch)
  for (int i = tid*8; i < 32*2048; i += NTHREADS*8)
    *(half8*)(wslice + i) = *(const half8*)(Wfs + i);
  bar();

// Dense HID->HID, all 16 waves (rt=w>>3, ct=w&7), weights from L2/L3.
#define DENSE(IN, OB, WT, BIAS) {                                          \
    const int rt = w >> 3, ct = w & 7;                                     \
    f32x4 acc = {0.f,0.f,0.f,0.f};                                         \
    _Pragma("unroll")                                                      \
    for (int kq = 0; kq < 4; ++kq){                                        \
      half8 a = *(const half8*)((IN) + SWZ(rt*16 + cl, kq*32 + 8*g));      \
      half8 b = *(const half8*)((WT) + ((ct*4 + kq)*64 + lane)*8);         \
      acc = __builtin_amdgcn_mfma_f32_16x16x32_f16(a, b, acc, 0,0,0);}     \
    float bn = (BIAS)[ct*16 + cl];                                         \
    _Pragma("unroll")                                                      \
    for (int r = 0; r < 4; ++r)                                            \
      (OB)[SWZ(rt*16 + 4*g + r, ct*16 + cl)] = (_Float16)fast_tanh(acc[r] + bn); }

// Decoder (hg==0 blocks, waves 0..3): rt=w>>1, ct=w&1
#define DECODER(TS) {                                                      \
    const int rt = w >> 1, ct = w & 1;                                     \
    f32x4 acc = {0.f,0.f,0.f,0.f};                                         \
    _Pragma("unroll")                                                      \
    for (int kq = 0; kq < 4; ++kq){                                        \
      half8 a = *(const half8*)(bufA + SWZ(rt*16 + cl, kq*32 + 8*g));      \
      half8 b = *(const half8*)(Wd + ((ct*4 + kq)*64 + lane)*8);           \
      acc = __builtin_amdgcn_mfma_f32_16x16x32_f16(a, b, acc, 0,0,0);}     \
    float bn = dec_b[ct*16 + cl];                                          \
    _Pragma("unroll")                                                      \
    for (int r = 0; r < 4; ++r)                                            \
      out[(b0 + rt*16 + 4*g + r)*(L_T*DOUT) + (TS)*DOUT + ct*16 + cl] = acc[r] + bn; }

  const int rt_b = w & 1, hp = w >> 1;   // biglayer mapping
  float dxlo[4], dxhi[4];

  for (int t = 0; t < L_T - 1; ++t){
    if (hg == 0 && w < 4) DECODER(t)   // z_t in bufA; reads drain at bar below

    float dt = times[t+1] - times[t];
    {
      int r = tid >> 5, d = tid & 31;
      const float* cp = coeffs + (b0 + r)*(L_T*DIN) + t*DIN + d;
      dxs[r][d] = (cp[DIN] - cp[0]) / dt;
    }
    bar();
#pragma unroll
    for (int r = 0; r < 4; ++r){
      dxlo[r] = dxs[rt_b*16 + 4*g + r][cl];
      dxhi[r] = dxs[rt_b*16 + 4*g + r][16 + cl];
    }

    for (int s = 0; s < 4; ++s){
      DENSE(bufA, bufB, W0, fb0)
      bar();
      DENSE(bufB, bufA, W1, fb1)
      bar();
      DENSE(bufA, bufB, W2, fb2)
      bar();

      // ---- biglayer from LDS-resident wslice: wave (rt_b, hp) -> h {2hp,2hp+1}
      {
        half8 af[4];
#pragma unroll
        for (int kq = 0; kq < 4; ++kq)
          af[kq] = *(const half8*)(bufB + SWZ(rt_b*16 + cl, kq*32 + 8*g));
#pragma unroll
        for (int hl2 = 0; hl2 < 2; ++hl2){
          const int hl = 2*hp + hl2;
          const _Float16* tpA = wslice + (2*hl)*2048 + lane*8;
          const _Float16* tpB = tpA + 2048;
          f32x4 aA = {0.f,0.f,0.f,0.f}, aB = {0.f,0.f,0.f,0.f};
#pragma unroll
          for (int j = 0; j < 4; ++j)
            aA = __builtin_amdgcn_mfma_f32_16x16x32_f16(af[j], *(const half8*)(tpA + 512*j), aA, 0,0,0);
#pragma unroll
          for (int j = 0; j < 4; ++j)
            aB = __builtin_amdgcn_mfma_f32_16x16x32_f16(af[j], *(const half8*)(tpB + 512*j), aB, 0,0,0);
          float bnA = fbfs[(2*hl)*16 + cl], bnB = fbfs[(2*hl + 1)*16 + cl];
          float p[4];
#pragma unroll
          for (int r = 0; r < 4; ++r)
            p[r] = fast_tanh(aA[r] + bnA)*dxlo[r] + fast_tanh(aB[r] + bnB)*dxhi[r];
#pragma unroll
          for (int m = 1; m < 16; m <<= 1){
#pragma unroll
            for (int r = 0; r < 4; ++r) p[r] += __shfl_xor(p[r], m, 64);
          }
          if (cl == 0){
#pragma unroll
            for (int r = 0; r < 4; ++r) dzs[rt_b*16 + 4*g + r][hl] = p[r];
          }
        }
      }
      bar();

      // ---- dz exchange via per-group flag sync (NO grid.sync)
      float* dbuf = dzg + ((4*t + s) & 1) * (B_TOT*HID);
      if (tid < 512){
        int br = tid >> 4, hl = tid & 15;
        dbuf[(b0 + br)*HID + hg*16 + hl] = dzs[br][hl];
      }
      asm volatile("s_waitcnt vmcnt(0)" ::: "memory");  // per-wave store-complete
      bar();                                            // all waves' stores done
      const unsigned int epoch = (unsigned int)(4*t + s + 1);
      if (tid == 0){
        __threadfence();                                // release: wbl2 to L3
        __hip_atomic_fetch_add(flag, 1u, __ATOMIC_RELAXED, __HIP_MEMORY_SCOPE_AGENT);
        while (__hip_atomic_load(flag, __ATOMIC_RELAXED, __HIP_MEMORY_SCOPE_AGENT)
               < 8u * epoch)
          __builtin_amdgcn_s_sleep(2);
        __threadfence();                                // acquire: inv stale L2
      }
      bar();                                            // broadcast readiness
      float kv[4];
      {
        const float* src = dbuf + (b0 + cr)*HID + cc;
#pragma unroll
        for (int j = 0; j < 4; ++j) kv[j] = src[j];
      }
      // ---- RK4 combine (state in registers, 4 elems/thread)
#pragma unroll
      for (int j = 0; j < 4; ++j){
        float nin;
        if (s == 0){ ka[j] = kv[j];        nin = zf[j] + 0.5f*dt*kv[j]; }
        else if (s == 1){ ka[j] += 2.f*kv[j]; nin = zf[j] + 0.5f*dt*kv[j]; }
        else if (s == 2){ ka[j] += 2.f*kv[j]; nin = zf[j] + dt*kv[j]; }
        else { zf[j] += (dt*(1.f/6.f))*(ka[j] + kv[j]); nin = zf[j]; }
        bufA[SWZ(cr, cc + j)] = (_Float16)nin;
      }
      bar();
    }
  }
  if (hg == 0 && w < 4) DECODER(L_T - 1)
}

extern "C" void kernel_launch(void* const* d_in, const int* in_sizes, int n_in,
                              void* d_out, int out_size, void* d_ws, size_t ws_size,
                              hipStream_t stream){
  const float* coeffs = (const float*)d_in[0];
  const float* times  = (const float*)d_in[1];
  const float* init_w = (const float*)d_in[2];
  const float* init_b = (const float*)d_in[3];
  const float* fw0    = (const float*)d_in[4];
  const float* fb0    = (const float*)d_in[5];
  const float* fw1    = (const float*)d_in[6];
  const float* fb1    = (const float*)d_in[7];
  const float* fw2    = (const float*)d_in[8];
  const float* fb2    = (const float*)d_in[9];
  const float* fwf    = (const float*)d_in[10];
  const float* fbf    = (const float*)d_in[11];
  const float* dec_w  = (const float*)d_in[12];
  const float* dec_b  = (const float*)d_in[13];
  _Float16* W  = (_Float16*)d_ws;
  float* dzg   = (float*)((char*)d_ws + 1163264);        // 2 x 1024x128 f32
  unsigned int* flags = (unsigned int*)((char*)d_ws + 2211840); // 32 x 128B
  float* outf  = (float*)d_out;

  hipLaunchKernelGGL(reorder_w, dim3(64),   dim3(256), 0, stream, fw0, W,          128, 128);
  hipLaunchKernelGGL(reorder_w, dim3(64),   dim3(256), 0, stream, fw1, W + 16384,  128, 128);
  hipLaunchKernelGGL(reorder_w, dim3(64),   dim3(256), 0, stream, fw2, W + 32768,  128, 128);
  hipLaunchKernelGGL(reorder_w, dim3(2048), dim3(256), 0, stream, fwf, W + 49152,  4096, 128);
  hipLaunchKernelGGL(reorder_w, dim3(16),   dim3(256), 0, stream, init_w, W + 573440, 128, 32);
  hipLaunchKernelGGL(reorder_w, dim3(16),   dim3(256), 0, stream, dec_w,  W + 577536,  32, 128);
  hipMemsetAsync(flags, 0, 32 * 128, stream);   // epochs restart every launch

  void* kargs[] = {(void*)&coeffs, (void*)&times, (void*)&init_b, (void*)&fb0,
                   (void*)&fb1, (void*)&fb2, (void*)&fbf, (void*)&dec_b,
                   (void*)&W, (void*)&dzg, (void*)&flags, (void*)&outf};
  hipLaunchCooperativeKernel((const void*)cde_main, dim3(NBLK), dim3(NTHREADS),
                             kargs, 0, stream);
}

// Round 17
// 3263.580 us; speedup vs baseline: 4.2498x; 2.4415x over previous
//
#include <hip/hip_runtime.h>

#define B_TOT 1024
#define L_T   100
#define DIN   32
#define HID   128
#define DOUT  32
#define BT    32      // batch rows per block
#define NHG   8       // h-groups (fwf split 8 ways -> 128 KiB LDS slice)
#define NBLK  256     // 32 batch-tiles x 8 h-groups = 256 CUs, 1 block/CU
#define NTHREADS 1024 // 16 waves

typedef _Float16 half8 __attribute__((ext_vector_type(8)));
typedef float    f32x4 __attribute__((ext_vector_type(4)));

// XOR-swizzled index into a [rows][128] f16 LDS tile (conflict-free b128 reads)
#define SWZ(r,c) (((r) << 7) + ((c) ^ (((r) & 7) << 3)))

__device__ __forceinline__ float fast_exp2(float x){
#if __has_builtin(__builtin_amdgcn_exp2f)
  return __builtin_amdgcn_exp2f(x);
#else
  float r; asm("v_exp_f32 %0, %1\n\ts_nop 1" : "=v"(r) : "v"(x)); return r;
#endif
}
__device__ __forceinline__ float fast_rcp(float x){
#if __has_builtin(__builtin_amdgcn_rcpf)
  return __builtin_amdgcn_rcpf(x);
#else
  float r; asm("v_rcp_f32 %0, %1\n\ts_nop 1" : "=v"(r) : "v"(x)); return r;
#endif
}
__device__ __forceinline__ float fast_tanh(float x){
  float e = fast_exp2(x * 2.885390081777926f);  // 2*log2(e)
  return 1.0f - 2.0f * fast_rcp(e + 1.0f);
}

// Reorder [N][K] f32 row-major weights into fragment-ready f16 tiles:
// dst[((tile*(K/32)+k0)*64 + lane)*8 + ki], lane = (n&15) + 16*((k>>3)&3)
__global__ void reorder_w(const float* __restrict__ src, _Float16* __restrict__ dst,
                          int N, int K){
  int id = blockIdx.x * 256 + threadIdx.x;
  if (id >= N * K) return;
  int n = id / K, k = id - n * K;
  int tile = n >> 4, nl = n & 15;
  int kq = (k >> 3) & 3, k0 = k >> 5, ki = k & 7;
  int lane = nl + (kq << 4);
  int K32 = K >> 5;
  dst[(((tile * K32 + k0) << 6) + lane) * 8 + ki] = (_Float16)src[id];
}

// h-split (fwf LDS-resident) + per-batch-group flag sync. Round-16 lesson:
// threadfence acquire/release = full L2 inv/wbl2 every stage (891 MB refetch,
// 15 us/stage). Here NO fences: dz moves through the coherence point itself —
// producer uses device-scope atomic stores (sc0 sc1, write-through L3),
// vmcnt(0)-drained BEFORE the flag add; consumer spins relaxed then reads dz
// with device-scope atomic loads (bypass stale local L2). L2 stays warm.
__global__ __launch_bounds__(NTHREADS) void cde_main(
    const float* __restrict__ coeffs, const float* __restrict__ times,
    const float* __restrict__ init_b, const float* __restrict__ fb0,
    const float* __restrict__ fb1,    const float* __restrict__ fb2,
    const float* __restrict__ fbf,    const float* __restrict__ dec_b,
    const _Float16* __restrict__ W,   float* __restrict__ dzg,
    unsigned int* __restrict__ flags, float* __restrict__ out)
{
  __shared__ _Float16 wslice[32*2048]; // 128 KiB: this block's fwf tiles (resident)
  __shared__ _Float16 bufA[BT*HID];    // 8 KiB ping-pong activations (f16, swizzled)
  __shared__ _Float16 bufB[BT*HID];    // 8 KiB
  __shared__ float    dzs[BT][16];     // 2 KiB  dz slice staging
  __shared__ float    dxs[BT][DIN];    // 4 KiB  dX/dt
  __shared__ float    fbfs[512];       // 2 KiB  fbf slice
  // total 155,648 B < 160 KiB

  const int tid  = threadIdx.x;
  const int lane = tid & 63;
  const int w    = tid >> 6;   // wave 0..15
  const int cl   = lane & 15;
  const int g    = lane >> 4;
  const int hg   = blockIdx.x & 7;   // h-group
  const int bt   = blockIdx.x >> 3;  // batch tile
  const int b0   = bt * BT;
  const int cr   = tid >> 5;         // combine row 0..31
  const int cc   = (tid & 31) * 4;   // combine col base

  const _Float16* W0 = W;
  const _Float16* W1 = W + 16384;
  const _Float16* W2 = W + 32768;
  const _Float16* Wf = W + 49152;   // fwf: 256 tiles
  const _Float16* Wi = W + 573440;  // init_w
  const _Float16* Wd = W + 577536;  // dec_w
  const _Float16* Wfs = Wf + hg * 32 * 2048;  // this block's 32 tiles
  unsigned int* flag = flags + bt * 32;       // 128B-strided counter per group

  // lgkm-only local barrier (two-sided clobbers + sched pins).
  auto bar = [&]{
    __builtin_amdgcn_sched_barrier(0);
    asm volatile("s_waitcnt lgkmcnt(0)" ::: "memory");
    __builtin_amdgcn_s_barrier();
    __builtin_amdgcn_sched_barrier(0);
    asm volatile("" ::: "memory");
  };

  // fbf slice (global idx = 512*hg + t_local*16 + nl)
  if (tid < 512) fbfs[tid] = fbf[hg*512 + tid];

  // ---- init: z0 = coeffs[:,0,:] @ init_w.T + init_b (wslice as f32 scratch)
  float* scratch = (float*)wslice;   // [32][128] f32, overwritten later
  {
    int r = tid >> 5, d = tid & 31;
    bufB[SWZ(r, d)] = (_Float16)coeffs[(b0 + r)*(L_T*DIN) + d];
  }
  bar();
  {
    const int rt = w >> 3, ct = w & 7;
    f32x4 acc = {0.f,0.f,0.f,0.f};
    half8 a = *(const half8*)(bufB + SWZ(rt*16 + cl, 8*g));
    half8 b = *(const half8*)(Wi + (ct*64 + lane)*8);
    acc = __builtin_amdgcn_mfma_f32_16x16x32_f16(a, b, acc, 0, 0, 0);
    float bn = init_b[ct*16 + cl];
#pragma unroll
    for (int r = 0; r < 4; ++r){
      float v = acc[r] + bn;
      scratch[(rt*16 + 4*g + r)*128 + ct*16 + cl] = v;
      bufA[SWZ(rt*16 + 4*g + r, ct*16 + cl)] = (_Float16)v;
    }
  }
  bar();
  float zf[4], ka[4] = {0.f,0.f,0.f,0.f};
#pragma unroll
  for (int j = 0; j < 4; ++j) zf[j] = scratch[cr*128 + cc + j];
  bar();
  // ---- fwf slice -> LDS (once; replaces scratch)
  for (int i = tid*8; i < 32*2048; i += NTHREADS*8)
    *(half8*)(wslice + i) = *(const half8*)(Wfs + i);
  bar();

// Dense HID->HID, all 16 waves (rt=w>>3, ct=w&7), weights from L2/L3.
#define DENSE(IN, OB, WT, BIAS) {                                          \
    const int rt = w >> 3, ct = w & 7;                                     \
    f32x4 acc = {0.f,0.f,0.f,0.f};                                         \
    _Pragma("unroll")                                                      \
    for (int kq = 0; kq < 4; ++kq){                                        \
      half8 a = *(const half8*)((IN) + SWZ(rt*16 + cl, kq*32 + 8*g));      \
      half8 b = *(const half8*)((WT) + ((ct*4 + kq)*64 + lane)*8);         \
      acc = __builtin_amdgcn_mfma_f32_16x16x32_f16(a, b, acc, 0,0,0);}     \
    float bn = (BIAS)[ct*16 + cl];                                         \
    _Pragma("unroll")                                                      \
    for (int r = 0; r < 4; ++r)                                            \
      (OB)[SWZ(rt*16 + 4*g + r, ct*16 + cl)] = (_Float16)fast_tanh(acc[r] + bn); }

// Decoder (hg==0 blocks, waves 0..3): rt=w>>1, ct=w&1
#define DECODER(TS) {                                                      \
    const int rt = w >> 1, ct = w & 1;                                     \
    f32x4 acc = {0.f,0.f,0.f,0.f};                                         \
    _Pragma("unroll")                                                      \
    for (int kq = 0; kq < 4; ++kq){                                        \
      half8 a = *(const half8*)(bufA + SWZ(rt*16 + cl, kq*32 + 8*g));      \
      half8 b = *(const half8*)(Wd + ((ct*4 + kq)*64 + lane)*8);           \
      acc = __builtin_amdgcn_mfma_f32_16x16x32_f16(a, b, acc, 0,0,0);}     \
    float bn = dec_b[ct*16 + cl];                                          \
    _Pragma("unroll")                                                      \
    for (int r = 0; r < 4; ++r)                                            \
      out[(b0 + rt*16 + 4*g + r)*(L_T*DOUT) + (TS)*DOUT + ct*16 + cl] = acc[r] + bn; }

  const int rt_b = w & 1, hp = w >> 1;   // biglayer mapping
  float dxlo[4], dxhi[4];

  for (int t = 0; t < L_T - 1; ++t){
    if (hg == 0 && w < 4) DECODER(t)   // z_t in bufA; reads drain at bar below

    float dt = times[t+1] - times[t];
    {
      int r = tid >> 5, d = tid & 31;
      const float* cp = coeffs + (b0 + r)*(L_T*DIN) + t*DIN + d;
      dxs[r][d] = (cp[DIN] - cp[0]) / dt;
    }
    bar();
#pragma unroll
    for (int r = 0; r < 4; ++r){
      dxlo[r] = dxs[rt_b*16 + 4*g + r][cl];
      dxhi[r] = dxs[rt_b*16 + 4*g + r][16 + cl];
    }

    for (int s = 0; s < 4; ++s){
      DENSE(bufA, bufB, W0, fb0)
      bar();
      DENSE(bufB, bufA, W1, fb1)
      bar();
      DENSE(bufA, bufB, W2, fb2)
      bar();

      // ---- biglayer from LDS-resident wslice: wave (rt_b, hp) -> h {2hp,2hp+1}
      {
        half8 af[4];
#pragma unroll
        for (int kq = 0; kq < 4; ++kq)
          af[kq] = *(const half8*)(bufB + SWZ(rt_b*16 + cl, kq*32 + 8*g));
#pragma unroll
        for (int hl2 = 0; hl2 < 2; ++hl2){
          const int hl = 2*hp + hl2;
          const _Float16* tpA = wslice + (2*hl)*2048 + lane*8;
          const _Float16* tpB = tpA + 2048;
          f32x4 aA = {0.f,0.f,0.f,0.f}, aB = {0.f,0.f,0.f,0.f};
#pragma unroll
          for (int j = 0; j < 4; ++j)
            aA = __builtin_amdgcn_mfma_f32_16x16x32_f16(af[j], *(const half8*)(tpA + 512*j), aA, 0,0,0);
#pragma unroll
          for (int j = 0; j < 4; ++j)
            aB = __builtin_amdgcn_mfma_f32_16x16x32_f16(af[j], *(const half8*)(tpB + 512*j), aB, 0,0,0);
          float bnA = fbfs[(2*hl)*16 + cl], bnB = fbfs[(2*hl + 1)*16 + cl];
          float p[4];
#pragma unroll
          for (int r = 0; r < 4; ++r)
            p[r] = fast_tanh(aA[r] + bnA)*dxlo[r] + fast_tanh(aB[r] + bnB)*dxhi[r];
#pragma unroll
          for (int m = 1; m < 16; m <<= 1){
#pragma unroll
            for (int r = 0; r < 4; ++r) p[r] += __shfl_xor(p[r], m, 64);
          }
          if (cl == 0){
#pragma unroll
            for (int r = 0; r < 4; ++r) dzs[rt_b*16 + 4*g + r][hl] = p[r];
          }
        }
      }
      bar();

      // ---- dz exchange: coherent stores -> flag -> coherent loads (NO fences)
      float* dbuf = dzg + ((4*t + s) & 1) * (B_TOT*HID);
      if (tid < 512){
        int br = tid >> 4, hl = tid & 15;
        __hip_atomic_store(&dbuf[(b0 + br)*HID + hg*16 + hl], dzs[br][hl],
                           __ATOMIC_RELAXED, __HIP_MEMORY_SCOPE_AGENT);
      }
      asm volatile("s_waitcnt vmcnt(0)" ::: "memory");  // dz at coherence point
      bar();                                            // all waves' stores done
      const unsigned int epoch = (unsigned int)(4*t + s + 1);
      if (tid == 0){
        __hip_atomic_fetch_add(flag, 1u, __ATOMIC_RELAXED, __HIP_MEMORY_SCOPE_AGENT);
        while (__hip_atomic_load(flag, __ATOMIC_RELAXED, __HIP_MEMORY_SCOPE_AGENT)
               < 8u * epoch)
          __builtin_amdgcn_s_sleep(2);
      }
      bar();                                            // broadcast readiness
      float kv[4];
      {
        const float* src = dbuf + (b0 + cr)*HID + cc;
#pragma unroll
        for (int j = 0; j < 4; ++j)
          kv[j] = __hip_atomic_load(&src[j], __ATOMIC_RELAXED,
                                    __HIP_MEMORY_SCOPE_AGENT);
      }
      // ---- RK4 combine (state in registers, 4 elems/thread)
#pragma unroll
      for (int j = 0; j < 4; ++j){
        float nin;
        if (s == 0){ ka[j] = kv[j];        nin = zf[j] + 0.5f*dt*kv[j]; }
        else if (s == 1){ ka[j] += 2.f*kv[j]; nin = zf[j] + 0.5f*dt*kv[j]; }
        else if (s == 2){ ka[j] += 2.f*kv[j]; nin = zf[j] + dt*kv[j]; }
        else { zf[j] += (dt*(1.f/6.f))*(ka[j] + kv[j]); nin = zf[j]; }
        bufA[SWZ(cr, cc + j)] = (_Float16)nin;
      }
      bar();
    }
  }
  if (hg == 0 && w < 4) DECODER(L_T - 1)
}

extern "C" void kernel_launch(void* const* d_in, const int* in_sizes, int n_in,
                              void* d_out, int out_size, void* d_ws, size_t ws_size,
                              hipStream_t stream){
  const float* coeffs = (const float*)d_in[0];
  const float* times  = (const float*)d_in[1];
  const float* init_w = (const float*)d_in[2];
  const float* init_b = (const float*)d_in[3];
  const float* fw0    = (const float*)d_in[4];
  const float* fb0    = (const float*)d_in[5];
  const float* fw1    = (const float*)d_in[6];
  const float* fb1    = (const float*)d_in[7];
  const float* fw2    = (const float*)d_in[8];
  const float* fb2    = (const float*)d_in[9];
  const float* fwf    = (const float*)d_in[10];
  const float* fbf    = (const float*)d_in[11];
  const float* dec_w  = (const float*)d_in[12];
  const float* dec_b  = (const float*)d_in[13];
  _Float16* W  = (_Float16*)d_ws;
  float* dzg   = (float*)((char*)d_ws + 1163264);        // 2 x 1024x128 f32
  unsigned int* flags = (unsigned int*)((char*)d_ws + 2211840); // 32 x 128B
  float* outf  = (float*)d_out;

  hipLaunchKernelGGL(reorder_w, dim3(64),   dim3(256), 0, stream, fw0, W,          128, 128);
  hipLaunchKernelGGL(reorder_w, dim3(64),   dim3(256), 0, stream, fw1, W + 16384,  128, 128);
  hipLaunchKernelGGL(reorder_w, dim3(64),   dim3(256), 0, stream, fw2, W + 32768,  128, 128);
  hipLaunchKernelGGL(reorder_w, dim3(2048), dim3(256), 0, stream, fwf, W + 49152,  4096, 128);
  hipLaunchKernelGGL(reorder_w, dim3(16),   dim3(256), 0, stream, init_w, W + 573440, 128, 32);
  hipLaunchKernelGGL(reorder_w, dim3(16),   dim3(256), 0, stream, dec_w,  W + 577536,  32, 128);
  hipMemsetAsync(flags, 0, 32 * 128, stream);   // epochs restart every launch

  void* kargs[] = {(void*)&coeffs, (void*)&times, (void*)&init_b, (void*)&fb0,
                   (void*)&fb1, (void*)&fb2, (void*)&fbf, (void*)&dec_b,
                   (void*)&W, (void*)&dzg, (void*)&flags, (void*)&outf};
  hipLaunchCooperativeKernel((const void*)cde_main, dim3(NBLK), dim3(NTHREADS),
                             kargs, 0, stream);
}